// Round 1
// baseline (278.671 us; speedup 1.0000x reference)
//
#include <hip/hip_runtime.h>
#include <hip/hip_bf16.h>

// GraphNet2: N=50000 nodes, E=1.6M edges, F=128.
// Pipeline:
//   vodes = relu(nodes @ W_enc + b_enc)              [N,32]
//   msg   = segment_sum(vodes[senders], receivers)   [N,32]
//   infl  = (vodes+msg, nodes[:,-1]) @ W_inf + b_inf [N,1]
//   att   = softmax(infl, axis=0)
//   g     = sum(att * (nodes @ W_emb + b_emb))       [12]
//   head MLP -> (logits/10, value)                   5 floats out
//
// Trick: msg only feeds dot(., W_inf[:32]) -> push the dot through the
// segment sum: p[n] = dot(relu-vodes[n], W_inf[:32]); edge pass is a single
// scalar atomicAdd(infl[recv], p[send]) instead of 32 atomics per edge.

#define NF 128
#define DENC 32
#define DEMB 12
#define DH 128

__global__ __launch_bounds__(256) void k1_node(
    const float* __restrict__ nodes,
    const float* __restrict__ W_enc, const float* __restrict__ b_enc,
    const float* __restrict__ W_inf, const float* __restrict__ b_inf,
    const float* __restrict__ W_emb, const float* __restrict__ b_emb,
    float* __restrict__ p, float* __restrict__ infl, float* __restrict__ embT,
    int n_nodes)
{
    int n = blockIdx.x * 256 + threadIdx.x;
    if (n >= n_nodes) return;
    const float4* x4p = (const float4*)(nodes + (size_t)n * NF);

    float vod[DENC];
    float em[DEMB];
#pragma unroll
    for (int j = 0; j < DENC; j++) vod[j] = b_enc[j];
#pragma unroll
    for (int j = 0; j < DEMB; j++) em[j] = b_emb[j];

    float x127 = 0.f;
#pragma unroll 2
    for (int k4 = 0; k4 < NF / 4; k4++) {
        float4 x4 = x4p[k4];
        int k = k4 * 4;
#pragma unroll
        for (int u = 0; u < 4; u++) {
            float xv = (u == 0) ? x4.x : (u == 1) ? x4.y : (u == 2) ? x4.z : x4.w;
#pragma unroll
            for (int j = 0; j < DENC; j++)
                vod[j] = fmaf(xv, W_enc[(k + u) * DENC + j], vod[j]);
#pragma unroll
            for (int j = 0; j < DEMB; j++)
                em[j] = fmaf(xv, W_emb[(k + u) * DEMB + j], em[j]);
        }
        if (k4 == NF / 4 - 1) x127 = x4.w;
    }

    float pn = 0.f;
#pragma unroll
    for (int j = 0; j < DENC; j++)
        pn += fmaxf(vod[j], 0.f) * W_inf[j];

    p[n] = pn;
    infl[n] = pn + x127 * W_inf[DENC] + b_inf[0];
#pragma unroll
    for (int j = 0; j < DEMB; j++)
        embT[(size_t)j * n_nodes + n] = em[j];
}

__global__ __launch_bounds__(256) void k2_edge(
    const int* __restrict__ senders, const int* __restrict__ receivers,
    const float* __restrict__ p, float* __restrict__ infl, int n_edges)
{
    int e = blockIdx.x * 256 + threadIdx.x;
    if (e < n_edges) {
        int s = senders[e];
        int r = receivers[e];
        atomicAdd(infl + r, p[s]);
    }
}

__global__ __launch_bounds__(256) void k3_max(
    const float* __restrict__ infl, float* __restrict__ pmax, int n_nodes)
{
    int tid = threadIdx.x;
    float m = -1e30f;
    for (int n = blockIdx.x * 256 + tid; n < n_nodes; n += gridDim.x * 256)
        m = fmaxf(m, infl[n]);
#pragma unroll
    for (int off = 32; off; off >>= 1)
        m = fmaxf(m, __shfl_down(m, off, 64));
    __shared__ float sm[4];
    int w = tid >> 6, l = tid & 63;
    if (l == 0) sm[w] = m;
    __syncthreads();
    if (tid == 0) {
        float mm = fmaxf(fmaxf(sm[0], sm[1]), fmaxf(sm[2], sm[3]));
        pmax[blockIdx.x] = mm;
    }
}

__global__ __launch_bounds__(256) void k4_sum(
    const float* __restrict__ infl, const float* __restrict__ embT,
    const float* __restrict__ pmax, float* __restrict__ psum,
    int n_nodes, int nmaxblk)
{
    int tid = threadIdx.x;
    float m = pmax[0];
    for (int i = 1; i < nmaxblk; i++) m = fmaxf(m, pmax[i]);

    float vals[13];
#pragma unroll
    for (int v = 0; v < 13; v++) vals[v] = 0.f;

    for (int n = blockIdx.x * 256 + tid; n < n_nodes; n += gridDim.x * 256) {
        float w = expf(infl[n] - m);
        vals[0] += w;
#pragma unroll
        for (int j = 0; j < DEMB; j++)
            vals[1 + j] = fmaf(w, embT[(size_t)j * n_nodes + n], vals[1 + j]);
    }

    __shared__ float red[4][13];
    int w = tid >> 6, l = tid & 63;
#pragma unroll
    for (int v = 0; v < 13; v++) {
        float x = vals[v];
#pragma unroll
        for (int off = 32; off; off >>= 1)
            x += __shfl_down(x, off, 64);
        if (l == 0) red[w][v] = x;
    }
    __syncthreads();
    if (tid < 13) {
        float s = red[0][tid] + red[1][tid] + red[2][tid] + red[3][tid];
        psum[blockIdx.x * 13 + tid] = s;
    }
}

__global__ __launch_bounds__(128) void k5_final(
    const float* __restrict__ psum,
    const float* __restrict__ W1, const float* __restrict__ b1,
    const float* __restrict__ W2, const float* __restrict__ b2,
    const float* __restrict__ Wy, const float* __restrict__ by,
    const float* __restrict__ Wx, const float* __restrict__ bx,
    float* __restrict__ out, int nblk)
{
    __shared__ float acc[13];
    __shared__ float g[DEMB];
    __shared__ float h1[DH];
    __shared__ float h2[DH];
    int t = threadIdx.x;

    if (t < 13) {
        float s = 0.f;
        for (int b = 0; b < nblk; b++) s += psum[b * 13 + t];
        acc[t] = s;
    }
    __syncthreads();
    if (t < DEMB) g[t] = acc[1 + t] / acc[0];
    __syncthreads();

    // h1 = relu(g @ W1 + b1), W1 is [12,128]
    float s1 = b1[t];
#pragma unroll
    for (int i = 0; i < DEMB; i++) s1 = fmaf(g[i], W1[i * DH + t], s1);
    h1[t] = fmaxf(s1, 0.f);
    __syncthreads();

    // h2 = relu(h1 @ W2 + b2), W2 is [128,128]
    float s2 = b2[t];
    for (int i = 0; i < DH; i++) s2 = fmaf(h1[i], W2[i * DH + t], s2);
    h2[t] = fmaxf(s2, 0.f);
    __syncthreads();

    if (t < 4) {
        float l = bx[t];
        for (int i = 0; i < DH; i++) l = fmaf(h2[i], Wx[i * 4 + t], l);
        out[t] = l / 10.0f;
    } else if (t == 4) {
        float v = by[0];
        for (int i = 0; i < DH; i++) v = fmaf(h2[i], Wy[i], v);
        out[4] = v;
    }
}

extern "C" void kernel_launch(void* const* d_in, const int* in_sizes, int n_in,
                              void* d_out, int out_size, void* d_ws, size_t ws_size,
                              hipStream_t stream) {
    const float* nodes   = (const float*)d_in[0];
    const int*   senders = (const int*)d_in[1];
    const int*   recvs   = (const int*)d_in[2];
    const float* W_enc   = (const float*)d_in[3];
    const float* b_enc   = (const float*)d_in[4];
    const float* W_inf   = (const float*)d_in[5];
    const float* b_inf   = (const float*)d_in[6];
    const float* W_emb   = (const float*)d_in[7];
    const float* b_emb   = (const float*)d_in[8];
    const float* W1      = (const float*)d_in[9];
    const float* b1      = (const float*)d_in[10];
    const float* W2      = (const float*)d_in[11];
    const float* b2      = (const float*)d_in[12];
    const float* Wy      = (const float*)d_in[13];
    const float* by      = (const float*)d_in[14];
    const float* Wx      = (const float*)d_in[15];
    const float* bx      = (const float*)d_in[16];
    float* out = (float*)d_out;

    const int n_nodes = in_sizes[0] / NF;   // 50000
    const int n_edges = in_sizes[1];        // 1600000

    // workspace layout (floats)
    float* ws    = (float*)d_ws;
    float* p     = ws;                               // [N]
    float* infl  = ws + n_nodes;                     // [N]
    float* embT  = ws + 2 * (size_t)n_nodes;         // [12][N]
    float* pmax  = ws + 14 * (size_t)n_nodes;        // [128]
    float* psum  = pmax + 128;                       // [128*13]

    const int NMAXBLK = 128;
    const int NSUMBLK = 128;

    hipLaunchKernelGGL(k1_node, dim3((n_nodes + 255) / 256), dim3(256), 0, stream,
                       nodes, W_enc, b_enc, W_inf, b_inf, W_emb, b_emb,
                       p, infl, embT, n_nodes);
    hipLaunchKernelGGL(k2_edge, dim3((n_edges + 255) / 256), dim3(256), 0, stream,
                       senders, recvs, p, infl, n_edges);
    hipLaunchKernelGGL(k3_max, dim3(NMAXBLK), dim3(256), 0, stream,
                       infl, pmax, n_nodes);
    hipLaunchKernelGGL(k4_sum, dim3(NSUMBLK), dim3(256), 0, stream,
                       infl, embT, pmax, psum, n_nodes, NMAXBLK);
    hipLaunchKernelGGL(k5_final, dim3(1), dim3(128), 0, stream,
                       psum, W1, b1, W2, b2, Wy, by, Wx, bx, out, NSUMBLK);
}

// Round 2
// 230.350 us; speedup vs baseline: 1.2098x; 1.2098x over previous
//
#include <hip/hip_runtime.h>
#include <hip/hip_bf16.h>

// GraphNet2: N=50000 nodes, E=1.6M edges, F=128.
//   vodes = relu(nodes @ W_enc + b_enc)              [N,32]
//   msg   = segment_sum(vodes[senders], receivers)   [N,32]
//   infl  = (vodes+msg, nodes[:,-1]) @ W_inf + b_inf [N,1]
//   att   = softmax(infl, axis=0)
//   g     = sum(att * (nodes @ W_emb + b_emb))       [12]
//   head MLP -> (logits/10, value)                   5 floats out
//
// R1 lesson: global atomicAdd scatter = 91us, WRITE_SIZE 49.8MB for a 200KB
// array -> device-scope atomics write through the non-coherent XCD L2s at
// 32B/op. Replace with LDS-privatized scatter (no global atomics at all):
// 128 blocks x 64KB LDS table x 4 node-range passes -> replica[128][N],
// then a register-space reduce fused with streaming-softmax partials.

#define NF 128
#define DENC 32
#define DEMB 12
#define DH 128

#define B_SCAT 128     // scatter blocks / replicas
#define R_SCAT 16000   // LDS table entries (64000 B, under 64KB static limit)
#define NPASS 4        // ceil(50000/16000)

// ---------------- K1: per-node encode -------------------------------------
__global__ __launch_bounds__(256) void k1_node(
    const float* __restrict__ nodes,
    const float* __restrict__ W_enc, const float* __restrict__ b_enc,
    const float* __restrict__ W_inf, const float* __restrict__ b_inf,
    const float* __restrict__ W_emb, const float* __restrict__ b_emb,
    float* __restrict__ p, float* __restrict__ inflb, float* __restrict__ embT,
    int n_nodes)
{
    int n = blockIdx.x * 256 + threadIdx.x;
    if (n >= n_nodes) return;
    const float4* x4p = (const float4*)(nodes + (size_t)n * NF);

    float vod[DENC];
    float em[DEMB];
#pragma unroll
    for (int j = 0; j < DENC; j++) vod[j] = b_enc[j];
#pragma unroll
    for (int j = 0; j < DEMB; j++) em[j] = b_emb[j];

    float x127 = 0.f;
#pragma unroll 2
    for (int k4 = 0; k4 < NF / 4; k4++) {
        float4 x4 = x4p[k4];
        int k = k4 * 4;
#pragma unroll
        for (int u = 0; u < 4; u++) {
            float xv = (u == 0) ? x4.x : (u == 1) ? x4.y : (u == 2) ? x4.z : x4.w;
#pragma unroll
            for (int j = 0; j < DENC; j++)
                vod[j] = fmaf(xv, W_enc[(k + u) * DENC + j], vod[j]);
#pragma unroll
            for (int j = 0; j < DEMB; j++)
                em[j] = fmaf(xv, W_emb[(k + u) * DEMB + j], em[j]);
        }
        if (k4 == NF / 4 - 1) x127 = x4.w;
    }

    float pn = 0.f;
#pragma unroll
    for (int j = 0; j < DENC; j++)
        pn += fmaxf(vod[j], 0.f) * W_inf[j];

    p[n] = pn;
    inflb[n] = pn + x127 * W_inf[DENC] + b_inf[0];
#pragma unroll
    for (int j = 0; j < DEMB; j++)
        embT[(size_t)j * n_nodes + n] = em[j];
}

// ---------------- K2: LDS-privatized scatter ------------------------------
__global__ __launch_bounds__(512) void k2_scatter(
    const int* __restrict__ senders, const int* __restrict__ recvs,
    const float* __restrict__ p, float* __restrict__ rep,
    int n_nodes, int n_edges)
{
    __shared__ float tab[R_SCAT];
    const int b = blockIdx.x;
    const int e0 = (int)((long long)n_edges * b / B_SCAT);
    const int e1 = (int)((long long)n_edges * (b + 1) / B_SCAT);
    float* __restrict__ myrep = rep + (size_t)b * n_nodes;

    for (int pass = 0; pass < NPASS; pass++) {
        const int lo = pass * R_SCAT;
        const int rng = min(R_SCAT, n_nodes - lo);
        for (int i = threadIdx.x; i < rng; i += 512) tab[i] = 0.f;
        __syncthreads();

        for (int e = e0 + threadIdx.x; e < e1; e += 512) {
            int r = recvs[e];
            unsigned rr = (unsigned)(r - lo);
            if (rr < (unsigned)rng) {
                int s = senders[e];
                atomicAdd(&tab[rr], p[s]);   // ds_add_f32, no global atomic
            }
        }
        __syncthreads();

        for (int i = threadIdx.x; i < rng; i += 512)
            myrep[lo + i] = tab[i];
        __syncthreads();
    }
}

// ---------------- K3: replica reduce + streaming-softmax partials ---------
__global__ __launch_bounds__(256) void k3_softpart(
    const float* __restrict__ inflb, const float* __restrict__ rep,
    const float* __restrict__ embT, float* __restrict__ psum, int n_nodes)
{
    const int tid = threadIdx.x;
    const int n = blockIdx.x * 256 + tid;
    const bool ok = (n < n_nodes);

    float infl = -1e30f;
    if (ok) {
        infl = inflb[n];
        const float* r = rep + n;
#pragma unroll 8
        for (int b = 0; b < B_SCAT; b++)
            infl += r[(size_t)b * n_nodes];
    }

    // block max
    float m = infl;
#pragma unroll
    for (int off = 32; off; off >>= 1)
        m = fmaxf(m, __shfl_down(m, off, 64));
    __shared__ float smax[4];
    __shared__ float smb;
    const int w = tid >> 6, l = tid & 63;
    if (l == 0) smax[w] = m;
    __syncthreads();
    if (tid == 0)
        smb = fmaxf(fmaxf(smax[0], smax[1]), fmaxf(smax[2], smax[3]));
    __syncthreads();
    const float mblk = smb;

    const float wgt = ok ? expf(infl - mblk) : 0.f;

    float v13[13];
    v13[0] = wgt;
#pragma unroll
    for (int j = 0; j < DEMB; j++)
        v13[1 + j] = ok ? wgt * embT[(size_t)j * n_nodes + n] : 0.f;

    __shared__ float red[4][13];
#pragma unroll
    for (int v = 0; v < 13; v++) {
        float x = v13[v];
#pragma unroll
        for (int off = 32; off; off >>= 1)
            x += __shfl_down(x, off, 64);
        if (l == 0) red[w][v] = x;
    }
    __syncthreads();
    if (tid < 13)
        psum[blockIdx.x * 14 + 1 + tid] =
            red[0][tid] + red[1][tid] + red[2][tid] + red[3][tid];
    if (tid == 13)
        psum[blockIdx.x * 14] = mblk;
}

// ---------------- K4: merge partials + MLP head ---------------------------
__global__ __launch_bounds__(128) void k4_head(
    const float* __restrict__ psum,
    const float* __restrict__ W1, const float* __restrict__ b1,
    const float* __restrict__ W2, const float* __restrict__ b2,
    const float* __restrict__ Wy, const float* __restrict__ by,
    const float* __restrict__ Wx, const float* __restrict__ bx,
    float* __restrict__ out, int nblk)
{
    const int t = threadIdx.x;
    const int w = t >> 6, l = t & 63;

    // global max of per-block maxima
    float m = -1e30f;
    for (int b = t; b < nblk; b += 128) m = fmaxf(m, psum[b * 14]);
#pragma unroll
    for (int off = 32; off; off >>= 1)
        m = fmaxf(m, __shfl_down(m, off, 64));
    __shared__ float s2[2];
    __shared__ float sM;
    if (l == 0) s2[w] = m;
    __syncthreads();
    if (t == 0) sM = fmaxf(s2[0], s2[1]);
    __syncthreads();
    const float M = sM;

    float acc[13];
#pragma unroll
    for (int v = 0; v < 13; v++) acc[v] = 0.f;
    for (int b = t; b < nblk; b += 128) {
        float sc = expf(psum[b * 14] - M);
#pragma unroll
        for (int v = 0; v < 13; v++)
            acc[v] = fmaf(sc, psum[b * 14 + 1 + v], acc[v]);
    }

    __shared__ float red[13][128];
#pragma unroll
    for (int v = 0; v < 13; v++) red[v][t] = acc[v];
    __syncthreads();
    for (int s = 64; s > 0; s >>= 1) {
        if (t < s) {
#pragma unroll
            for (int v = 0; v < 13; v++) red[v][t] += red[v][t + s];
        }
        __syncthreads();
    }

    __shared__ float g[DEMB];
    __shared__ float h1[DH];
    __shared__ float h2[DH];
    const float S = red[0][0];
    if (t < DEMB) g[t] = red[1 + t][0] / S;
    __syncthreads();

    float s1 = b1[t];
#pragma unroll
    for (int i = 0; i < DEMB; i++) s1 = fmaf(g[i], W1[i * DH + t], s1);
    h1[t] = fmaxf(s1, 0.f);
    __syncthreads();

    float s2v = b2[t];
    for (int i = 0; i < DH; i++) s2v = fmaf(h1[i], W2[i * DH + t], s2v);
    h2[t] = fmaxf(s2v, 0.f);
    __syncthreads();

    if (t < 4) {
        float lg = bx[t];
        for (int i = 0; i < DH; i++) lg = fmaf(h2[i], Wx[i * 4 + t], lg);
        out[t] = lg / 10.0f;
    } else if (t == 4) {
        float v = by[0];
        for (int i = 0; i < DH; i++) v = fmaf(h2[i], Wy[i], v);
        out[4] = v;
    }
}

extern "C" void kernel_launch(void* const* d_in, const int* in_sizes, int n_in,
                              void* d_out, int out_size, void* d_ws, size_t ws_size,
                              hipStream_t stream) {
    const float* nodes   = (const float*)d_in[0];
    const int*   senders = (const int*)d_in[1];
    const int*   recvs   = (const int*)d_in[2];
    const float* W_enc   = (const float*)d_in[3];
    const float* b_enc   = (const float*)d_in[4];
    const float* W_inf   = (const float*)d_in[5];
    const float* b_inf   = (const float*)d_in[6];
    const float* W_emb   = (const float*)d_in[7];
    const float* b_emb   = (const float*)d_in[8];
    const float* W1      = (const float*)d_in[9];
    const float* b1      = (const float*)d_in[10];
    const float* W2      = (const float*)d_in[11];
    const float* b2      = (const float*)d_in[12];
    const float* Wy      = (const float*)d_in[13];
    const float* by      = (const float*)d_in[14];
    const float* Wx      = (const float*)d_in[15];
    const float* bx      = (const float*)d_in[16];
    float* out = (float*)d_out;

    const int n_nodes = in_sizes[0] / NF;   // 50000
    const int n_edges = in_sizes[1];        // 1600000
    const int nblk3 = (n_nodes + 255) / 256;

    // workspace layout (floats):
    float* ws    = (float*)d_ws;
    float* p     = ws;                                   // [N]
    float* inflb = ws + n_nodes;                         // [N]
    float* embT  = ws + 2 * (size_t)n_nodes;             // [12][N]
    float* rep   = ws + 14 * (size_t)n_nodes;            // [128][N]
    float* psum  = ws + (14 + B_SCAT) * (size_t)n_nodes; // [nblk3*14]

    hipLaunchKernelGGL(k1_node, dim3((n_nodes + 255) / 256), dim3(256), 0, stream,
                       nodes, W_enc, b_enc, W_inf, b_inf, W_emb, b_emb,
                       p, inflb, embT, n_nodes);
    hipLaunchKernelGGL(k2_scatter, dim3(B_SCAT), dim3(512), 0, stream,
                       senders, recvs, p, rep, n_nodes, n_edges);
    hipLaunchKernelGGL(k3_softpart, dim3(nblk3), dim3(256), 0, stream,
                       inflb, rep, embT, psum, n_nodes);
    hipLaunchKernelGGL(k4_head, dim3(1), dim3(128), 0, stream,
                       psum, W1, b1, W2, b2, Wy, by, Wx, bx, out, nblk3);
}

// Round 3
// 228.916 us; speedup vs baseline: 1.2174x; 1.0063x over previous
//
#include <hip/hip_runtime.h>
#include <hip/hip_bf16.h>

// GraphNet2: N=50000 nodes, E=1.6M edges, F=128.
// R1: global atomics = 91us (32B/op write-through). -> LDS privatization.
// R2: 128-block scatter = 66us, Occupancy 9% (half the CUs idle, 4 serial
//     passes). Hidden 164us in k1/k3 (196-block launches, 0.77 waves/SIMD).
// R3: parallelism everywhere:
//   k1: 4 waves/node-group k-split, 782 blocks (weights stay s_load uniform)
//   k2: 512 blocks = 128 edge-slices x 4 range-owners, 1 pass each
//   k3a: replica reduce 4-way split, 782 blocks
//   k3b: softmax partials
//   k4: merge + MLP head

#define NF 128
#define DENC 32
#define DEMB 12
#define DH 128
#define NTOT 44        // DENC + DEMB

#define NSLICE 128     // replica rows
#define R_SCAT 16000   // LDS table entries (64000 B)
#define NRANGE 4       // node ranges (4*16000 >= 50000)

// ---------------- K1: per-node encode, 4-way k-split ----------------------
__global__ __launch_bounds__(256) void k1_node(
    const float* __restrict__ nodes,
    const float* __restrict__ W_enc, const float* __restrict__ b_enc,
    const float* __restrict__ W_inf, const float* __restrict__ b_inf,
    const float* __restrict__ W_emb, const float* __restrict__ b_emb,
    float* __restrict__ p, float* __restrict__ inflb, float* __restrict__ embT,
    int n_nodes)
{
    __shared__ float tab[64][NTOT + 1];   // stride 45: conflict-free
    const int tid  = threadIdx.x;
    const int lane = tid & 63;
    const int wv   = __builtin_amdgcn_readfirstlane(tid >> 6);  // 0..3
    const int node = blockIdx.x * 64 + lane;
    const bool ok  = (node < n_nodes);

    // zero merge table
    for (int i = tid; i < 64 * (NTOT + 1); i += 256)
        ((float*)tab)[i] = 0.f;
    __syncthreads();

    if (ok) {
        const int kbase = 32 * wv;
        const float4* x4p = (const float4*)(nodes + (size_t)node * NF) + 8 * wv;

        float4 x4[8];
#pragma unroll
        for (int i = 0; i < 8; i++) x4[i] = x4p[i];

        float vod[DENC];
        float em[DEMB];
#pragma unroll
        for (int j = 0; j < DENC; j++) vod[j] = 0.f;
#pragma unroll
        for (int j = 0; j < DEMB; j++) em[j] = 0.f;

#pragma unroll
        for (int i = 0; i < 8; i++) {
#pragma unroll
            for (int u = 0; u < 4; u++) {
                float xv = (u == 0) ? x4[i].x : (u == 1) ? x4[i].y
                         : (u == 2) ? x4[i].z : x4[i].w;
                const int k = kbase + 4 * i + u;   // wave-uniform -> s_load W
#pragma unroll
                for (int j = 0; j < DENC; j++)
                    vod[j] = fmaf(xv, W_enc[k * DENC + j], vod[j]);
#pragma unroll
                for (int j = 0; j < DEMB; j++)
                    em[j] = fmaf(xv, W_emb[k * DEMB + j], em[j]);
            }
        }
#pragma unroll
        for (int j = 0; j < DENC; j++) atomicAdd(&tab[lane][j], vod[j]);
#pragma unroll
        for (int j = 0; j < DEMB; j++) atomicAdd(&tab[lane][DENC + j], em[j]);
    }
    __syncthreads();

    // finalize: wave 0, one node per lane
    if (wv == 0 && ok) {
        float pn = 0.f;
#pragma unroll
        for (int j = 0; j < DENC; j++)
            pn += fmaxf(tab[lane][j] + b_enc[j], 0.f) * W_inf[j];
#pragma unroll
        for (int j = 0; j < DEMB; j++)
            embT[(size_t)j * n_nodes + node] = tab[lane][DENC + j] + b_emb[j];
        float x127 = nodes[(size_t)node * NF + (NF - 1)];
        p[node] = pn;
        inflb[node] = pn + x127 * W_inf[DENC] + b_inf[0];
    }
}

// ---------------- K2: LDS scatter, 128 slices x 4 range-owner blocks ------
__global__ __launch_bounds__(512) void k2_scatter(
    const int* __restrict__ senders, const int* __restrict__ recvs,
    const float* __restrict__ p, float* __restrict__ rep,
    int n_nodes, int n_edges)
{
    __shared__ float tab[R_SCAT];
    const int slice = blockIdx.x >> 2;       // 0..127  (edge slice)
    const int rng_i = blockIdx.x & 3;        // 0..3    (node range)
    const int e0 = (int)((long long)n_edges * slice / NSLICE);
    const int e1 = (int)((long long)n_edges * (slice + 1) / NSLICE);
    const int lo = rng_i * R_SCAT;
    const int rng = min(R_SCAT, n_nodes - lo);

    for (int i = threadIdx.x; i < rng; i += 512) tab[i] = 0.f;
    __syncthreads();

    for (int e = e0 + threadIdx.x; e < e1; e += 512) {
        int r = recvs[e];
        unsigned rr = (unsigned)(r - lo);
        if (rr < (unsigned)rng)
            atomicAdd(&tab[rr], p[senders[e]]);
    }
    __syncthreads();

    float* __restrict__ dst = rep + (size_t)slice * n_nodes + lo;
    for (int i = threadIdx.x; i < rng; i += 512)
        dst[i] = tab[i];
}

// ---------------- K3a: replica reduce (4-way split) -----------------------
__global__ __launch_bounds__(256) void k3a_reduce(
    const float* __restrict__ inflb, const float* __restrict__ rep,
    float* __restrict__ infl, int n_nodes)
{
    __shared__ float tab[64];
    const int tid  = threadIdx.x;
    const int lane = tid & 63;
    const int wv   = __builtin_amdgcn_readfirstlane(tid >> 6);
    const int node = blockIdx.x * 64 + lane;
    const bool ok  = (node < n_nodes);

    if (tid < 64) tab[tid] = 0.f;
    __syncthreads();

    if (ok) {
        const float* r = rep + (size_t)(32 * wv) * n_nodes + node;
        float s = 0.f;
#pragma unroll 8
        for (int i = 0; i < NSLICE / 4; i++)
            s += r[(size_t)i * n_nodes];
        atomicAdd(&tab[lane], s);
    }
    __syncthreads();

    if (wv == 0 && ok)
        infl[node] = inflb[node] + tab[lane];
}

// ---------------- K3b: streaming-softmax partials -------------------------
__global__ __launch_bounds__(256) void k3b_softpart(
    const float* __restrict__ infl, const float* __restrict__ embT,
    float* __restrict__ psum, int n_nodes)
{
    const int tid = threadIdx.x;
    const int n = blockIdx.x * 256 + tid;
    const bool ok = (n < n_nodes);

    const float x = ok ? infl[n] : -1e30f;

    float m = x;
#pragma unroll
    for (int off = 32; off; off >>= 1)
        m = fmaxf(m, __shfl_down(m, off, 64));
    __shared__ float smax[4];
    __shared__ float smb;
    const int w = tid >> 6, l = tid & 63;
    if (l == 0) smax[w] = m;
    __syncthreads();
    if (tid == 0)
        smb = fmaxf(fmaxf(smax[0], smax[1]), fmaxf(smax[2], smax[3]));
    __syncthreads();
    const float mblk = smb;

    const float wgt = ok ? expf(x - mblk) : 0.f;

    float v13[13];
    v13[0] = wgt;
#pragma unroll
    for (int j = 0; j < DEMB; j++)
        v13[1 + j] = ok ? wgt * embT[(size_t)j * n_nodes + n] : 0.f;

    __shared__ float red[4][13];
#pragma unroll
    for (int v = 0; v < 13; v++) {
        float xx = v13[v];
#pragma unroll
        for (int off = 32; off; off >>= 1)
            xx += __shfl_down(xx, off, 64);
        if (l == 0) red[w][v] = xx;
    }
    __syncthreads();
    if (tid < 13)
        psum[blockIdx.x * 14 + 1 + tid] =
            red[0][tid] + red[1][tid] + red[2][tid] + red[3][tid];
    if (tid == 13)
        psum[blockIdx.x * 14] = mblk;
}

// ---------------- K4: merge partials + MLP head ---------------------------
__global__ __launch_bounds__(128) void k4_head(
    const float* __restrict__ psum,
    const float* __restrict__ W1, const float* __restrict__ b1,
    const float* __restrict__ W2, const float* __restrict__ b2,
    const float* __restrict__ Wy, const float* __restrict__ by,
    const float* __restrict__ Wx, const float* __restrict__ bx,
    float* __restrict__ out, int nblk)
{
    const int t = threadIdx.x;
    const int w = t >> 6, l = t & 63;

    float m = -1e30f;
    for (int b = t; b < nblk; b += 128) m = fmaxf(m, psum[b * 14]);
#pragma unroll
    for (int off = 32; off; off >>= 1)
        m = fmaxf(m, __shfl_down(m, off, 64));
    __shared__ float s2[2];
    __shared__ float sM;
    if (l == 0) s2[w] = m;
    __syncthreads();
    if (t == 0) sM = fmaxf(s2[0], s2[1]);
    __syncthreads();
    const float M = sM;

    float acc[13];
#pragma unroll
    for (int v = 0; v < 13; v++) acc[v] = 0.f;
    for (int b = t; b < nblk; b += 128) {
        float sc = expf(psum[b * 14] - M);
#pragma unroll
        for (int v = 0; v < 13; v++)
            acc[v] = fmaf(sc, psum[b * 14 + 1 + v], acc[v]);
    }

    __shared__ float red2[2][13];
#pragma unroll
    for (int v = 0; v < 13; v++) {
        float xx = acc[v];
#pragma unroll
        for (int off = 32; off; off >>= 1)
            xx += __shfl_down(xx, off, 64);
        if (l == 0) red2[w][v] = xx;
    }
    __syncthreads();

    __shared__ float g[DEMB];
    __shared__ float h1[DH];
    __shared__ float h2[DH];
    if (t < DEMB) {
        float S = red2[0][0] + red2[1][0];
        g[t] = (red2[0][1 + t] + red2[1][1 + t]) / S;
    }
    __syncthreads();

    float s1 = b1[t];
#pragma unroll
    for (int i = 0; i < DEMB; i++) s1 = fmaf(g[i], W1[i * DH + t], s1);
    h1[t] = fmaxf(s1, 0.f);
    __syncthreads();

    float s2v = b2[t];
    for (int i = 0; i < DH; i++) s2v = fmaf(h1[i], W2[i * DH + t], s2v);
    h2[t] = fmaxf(s2v, 0.f);
    __syncthreads();

    if (t < 4) {
        float lg = bx[t];
        for (int i = 0; i < DH; i++) lg = fmaf(h2[i], Wx[i * 4 + t], lg);
        out[t] = lg / 10.0f;
    } else if (t == 4) {
        float v = by[0];
        for (int i = 0; i < DH; i++) v = fmaf(h2[i], Wy[i], v);
        out[4] = v;
    }
}

extern "C" void kernel_launch(void* const* d_in, const int* in_sizes, int n_in,
                              void* d_out, int out_size, void* d_ws, size_t ws_size,
                              hipStream_t stream) {
    const float* nodes   = (const float*)d_in[0];
    const int*   senders = (const int*)d_in[1];
    const int*   recvs   = (const int*)d_in[2];
    const float* W_enc   = (const float*)d_in[3];
    const float* b_enc   = (const float*)d_in[4];
    const float* W_inf   = (const float*)d_in[5];
    const float* b_inf   = (const float*)d_in[6];
    const float* W_emb   = (const float*)d_in[7];
    const float* b_emb   = (const float*)d_in[8];
    const float* W1      = (const float*)d_in[9];
    const float* b1      = (const float*)d_in[10];
    const float* W2      = (const float*)d_in[11];
    const float* b2      = (const float*)d_in[12];
    const float* Wy      = (const float*)d_in[13];
    const float* by      = (const float*)d_in[14];
    const float* Wx      = (const float*)d_in[15];
    const float* bx      = (const float*)d_in[16];
    float* out = (float*)d_out;

    const int n_nodes = in_sizes[0] / NF;   // 50000
    const int n_edges = in_sizes[1];        // 1600000
    const int nb64  = (n_nodes + 63) / 64;      // 782
    const int nblk3 = (n_nodes + 255) / 256;    // 196

    // workspace layout (floats):
    float* ws    = (float*)d_ws;
    float* p     = ws;                                    // [N]; reused as infl after k2
    float* inflb = ws + n_nodes;                          // [N]
    float* embT  = ws + 2 * (size_t)n_nodes;              // [12][N]
    float* rep   = ws + 14 * (size_t)n_nodes;             // [128][N]
    float* psum  = ws + (14 + NSLICE) * (size_t)n_nodes;  // [nblk3*14]
    float* infl  = p;  // p is dead after k2; alias

    hipLaunchKernelGGL(k1_node, dim3(nb64), dim3(256), 0, stream,
                       nodes, W_enc, b_enc, W_inf, b_inf, W_emb, b_emb,
                       p, inflb, embT, n_nodes);
    hipLaunchKernelGGL(k2_scatter, dim3(NSLICE * NRANGE), dim3(512), 0, stream,
                       senders, recvs, p, rep, n_nodes, n_edges);
    hipLaunchKernelGGL(k3a_reduce, dim3(nb64), dim3(256), 0, stream,
                       inflb, rep, infl, n_nodes);
    hipLaunchKernelGGL(k3b_softpart, dim3(nblk3), dim3(256), 0, stream,
                       infl, embT, psum, n_nodes);
    hipLaunchKernelGGL(k4_head, dim3(1), dim3(128), 0, stream,
                       psum, W1, b1, W2, b2, Wy, by, Wx, bx, out, nblk3);
}

// Round 4
// 159.705 us; speedup vs baseline: 1.7449x; 1.4334x over previous
//
#include <hip/hip_runtime.h>
#include <hip/hip_bf16.h>

// GraphNet2: N=50000 nodes, E=1.6M edges, F=128.
// R1: global atomic scatter 91us (32B/op write-through) -> LDS privatization.
// R2: 128-block scatter, occupancy 9% -> split ranges across blocks.
// R3: k1 k-split spilled (VGPR=32 vs ~76 needed -> scratch), 79us, VALU 9%.
// R4: k1 j-split: outputs are separable per-j, so waves own output slices
//     (11-12 accums each, no spills, weights stay s_load-uniform, merge = 3
//     floats/node in LDS). k3a+k3b fused. k2 edge scan int4-vectorized.

#define NF 128
#define DENC 32
#define DEMB 12
#define DH 128

#define NSLICE 128     // replica rows
#define R_SCAT 16000   // LDS table entries (64000 B)
#define NRANGE 4       // node ranges (4*16000 >= 50000)

// GEMV over one node row: acc[j] += x[k] * W[k*LDW + jbase + j], k=0..127.
// jbase is wave-uniform -> W/bias loads are s_loads. Also returns x[127].
template <int NJ, int LDW>
__device__ __forceinline__ void gemv_rows(
    const float4* __restrict__ x4p, const float* __restrict__ W,
    int jbase, const float* __restrict__ bias, float* acc, float& x_last)
{
#pragma unroll
    for (int j = 0; j < NJ; j++) acc[j] = bias[jbase + j];
#pragma unroll 2
    for (int c = 0; c < 8; c++) {
        float4 xa = x4p[4 * c + 0];
        float4 xb = x4p[4 * c + 1];
        float4 xc = x4p[4 * c + 2];
        float4 xd = x4p[4 * c + 3];
        float xs[16] = {xa.x, xa.y, xa.z, xa.w, xb.x, xb.y, xb.z, xb.w,
                        xc.x, xc.y, xc.z, xc.w, xd.x, xd.y, xd.z, xd.w};
#pragma unroll
        for (int u = 0; u < 16; u++) {
            const int k = 16 * c + u;
#pragma unroll
            for (int j = 0; j < NJ; j++)
                acc[j] = fmaf(xs[u], W[k * LDW + jbase + j], acc[j]);
        }
        if (c == 7) x_last = xd.w;
    }
}

// ---------------- K1: per-node encode, 4-way j-split ----------------------
__global__ __launch_bounds__(256) void k1_node(
    const float* __restrict__ nodes,
    const float* __restrict__ W_enc, const float* __restrict__ b_enc,
    const float* __restrict__ W_inf, const float* __restrict__ b_inf,
    const float* __restrict__ W_emb, const float* __restrict__ b_emb,
    float* __restrict__ p, float* __restrict__ inflb, float* __restrict__ embT,
    int n_nodes)
{
    __shared__ float tabp[3][64];
    const int tid  = threadIdx.x;
    const int lane = tid & 63;
    const int wv   = __builtin_amdgcn_readfirstlane(tid >> 6);  // 0..3
    const int node = blockIdx.x * 64 + lane;
    const bool ok  = (node < n_nodes);
    const float4* x4p = ok ? (const float4*)(nodes + (size_t)node * NF)
                           : (const float4*)nodes;

    float x127 = 0.f;
    if (wv == 3) {
        float acc[DEMB];
        gemv_rows<DEMB, DEMB>(x4p, W_emb, 0, b_emb, acc, x127);
        if (ok) {
#pragma unroll
            for (int j = 0; j < DEMB; j++)
                embT[(size_t)j * n_nodes + node] = acc[j];
        }
    } else {
        const int jbase = __builtin_amdgcn_readfirstlane(wv * 11);
        float pp = 0.f;
        if (wv == 2) {
            float acc[10];
            gemv_rows<10, DENC>(x4p, W_enc, jbase, b_enc, acc, x127);
#pragma unroll
            for (int j = 0; j < 10; j++)
                pp += fmaxf(acc[j], 0.f) * W_inf[jbase + j];
        } else {
            float acc[11];
            gemv_rows<11, DENC>(x4p, W_enc, jbase, b_enc, acc, x127);
#pragma unroll
            for (int j = 0; j < 11; j++)
                pp += fmaxf(acc[j], 0.f) * W_inf[jbase + j];
        }
        tabp[wv][lane] = pp;
    }
    __syncthreads();

    if (wv == 0 && ok) {
        float pn = tabp[0][lane] + tabp[1][lane] + tabp[2][lane];
        p[node] = pn;
        inflb[node] = pn + x127 * W_inf[DENC] + b_inf[0];
    }
}

// ---------------- K2: LDS scatter, 128 slices x 4 range-owner blocks ------
__global__ __launch_bounds__(512) void k2_scatter(
    const int* __restrict__ senders, const int* __restrict__ recvs,
    const float* __restrict__ p, float* __restrict__ rep,
    int n_nodes, int n_edges)
{
    __shared__ float tab[R_SCAT];
    const int slice = blockIdx.x >> 2;       // edge slice
    const int rng_i = blockIdx.x & 3;        // node range
    const int e0 = (int)((long long)n_edges * slice / NSLICE);
    const int e1 = (int)((long long)n_edges * (slice + 1) / NSLICE);
    const int lo = rng_i * R_SCAT;
    const int rng = min(R_SCAT, n_nodes - lo);

    float4* tab4 = (float4*)tab;
    for (int i = threadIdx.x; i < (rng + 3) / 4; i += 512)
        tab4[i] = make_float4(0.f, 0.f, 0.f, 0.f);
    __syncthreads();

    // aligned int4 main loop + scalar tails
    const int ae0 = (e0 + 3) & ~3;
    const int ae1 = e1 & ~3;
    for (int e = e0 + (int)threadIdx.x; e < ae0; e += 512) {
        int r = recvs[e];
        unsigned rr = (unsigned)(r - lo);
        if (rr < (unsigned)rng) atomicAdd(&tab[rr], p[senders[e]]);
    }
    const int4* r4 = (const int4*)recvs;
    const int4* s4 = (const int4*)senders;
    for (int i = ae0 / 4 + (int)threadIdx.x; i < ae1 / 4; i += 512) {
        int4 r = r4[i];
        int4 s = s4[i];
        unsigned rr;
        rr = (unsigned)(r.x - lo); if (rr < (unsigned)rng) atomicAdd(&tab[rr], p[s.x]);
        rr = (unsigned)(r.y - lo); if (rr < (unsigned)rng) atomicAdd(&tab[rr], p[s.y]);
        rr = (unsigned)(r.z - lo); if (rr < (unsigned)rng) atomicAdd(&tab[rr], p[s.z]);
        rr = (unsigned)(r.w - lo); if (rr < (unsigned)rng) atomicAdd(&tab[rr], p[s.w]);
    }
    for (int e = ae1 + (int)threadIdx.x; e < e1; e += 512) {
        int r = recvs[e];
        unsigned rr = (unsigned)(r - lo);
        if (rr < (unsigned)rng) atomicAdd(&tab[rr], p[senders[e]]);
    }
    __syncthreads();

    float* __restrict__ dst = rep + (size_t)slice * n_nodes + lo;
    for (int i = threadIdx.x; i < rng / 4; i += 512)
        ((float4*)dst)[i] = tab4[i];
    for (int i = (rng & ~3) + threadIdx.x; i < rng; i += 512)
        dst[i] = tab[i];
}

// ---------------- K3: replica reduce + softmax partials (fused) -----------
__global__ __launch_bounds__(256) void k3_soft(
    const float* __restrict__ inflb, const float* __restrict__ rep,
    const float* __restrict__ embT, float* __restrict__ psum, int n_nodes)
{
    __shared__ float tab[4][64];
    const int tid  = threadIdx.x;
    const int lane = tid & 63;
    const int wv   = __builtin_amdgcn_readfirstlane(tid >> 6);
    const int node = blockIdx.x * 64 + lane;
    const bool ok  = (node < n_nodes);

    float s = 0.f;
    if (ok) {
        const float* r = rep + (size_t)(32 * wv) * n_nodes + node;
#pragma unroll 8
        for (int i = 0; i < NSLICE / 4; i++)
            s += r[(size_t)i * n_nodes];
    }
    tab[wv][lane] = s;
    __syncthreads();

    if (wv == 0) {
        float infl = ok ? inflb[node] + tab[0][lane] + tab[1][lane]
                          + tab[2][lane] + tab[3][lane]
                        : -1e30f;
        float m = infl;
#pragma unroll
        for (int off = 32; off; off >>= 1)
            m = fmaxf(m, __shfl_down(m, off, 64));
        m = __shfl(m, 0, 64);

        const float w = ok ? expf(infl - m) : 0.f;
        float v13[13];
        v13[0] = w;
#pragma unroll
        for (int j = 0; j < DEMB; j++)
            v13[1 + j] = ok ? w * embT[(size_t)j * n_nodes + node] : 0.f;

#pragma unroll
        for (int v = 0; v < 13; v++) {
            float x = v13[v];
#pragma unroll
            for (int off = 32; off; off >>= 1)
                x += __shfl_down(x, off, 64);
            v13[v] = x;   // lane 0 holds the sum
        }
        if (lane == 0) {
            psum[blockIdx.x * 14] = m;
#pragma unroll
            for (int v = 0; v < 13; v++)
                psum[blockIdx.x * 14 + 1 + v] = v13[v];
        }
    }
}

// ---------------- K4: merge partials + MLP head ---------------------------
__global__ __launch_bounds__(128) void k4_head(
    const float* __restrict__ psum,
    const float* __restrict__ W1, const float* __restrict__ b1,
    const float* __restrict__ W2, const float* __restrict__ b2,
    const float* __restrict__ Wy, const float* __restrict__ by,
    const float* __restrict__ Wx, const float* __restrict__ bx,
    float* __restrict__ out, int nblk)
{
    const int t = threadIdx.x;
    const int w = t >> 6, l = t & 63;

    float m = -1e30f;
    for (int b = t; b < nblk; b += 128) m = fmaxf(m, psum[b * 14]);
#pragma unroll
    for (int off = 32; off; off >>= 1)
        m = fmaxf(m, __shfl_down(m, off, 64));
    __shared__ float s2[2];
    __shared__ float sM;
    if (l == 0) s2[w] = m;
    __syncthreads();
    if (t == 0) sM = fmaxf(s2[0], s2[1]);
    __syncthreads();
    const float M = sM;

    float acc[13];
#pragma unroll
    for (int v = 0; v < 13; v++) acc[v] = 0.f;
    for (int b = t; b < nblk; b += 128) {
        float sc = expf(psum[b * 14] - M);
#pragma unroll
        for (int v = 0; v < 13; v++)
            acc[v] = fmaf(sc, psum[b * 14 + 1 + v], acc[v]);
    }

    __shared__ float red2[2][13];
#pragma unroll
    for (int v = 0; v < 13; v++) {
        float xx = acc[v];
#pragma unroll
        for (int off = 32; off; off >>= 1)
            xx += __shfl_down(xx, off, 64);
        if (l == 0) red2[w][v] = xx;
    }
    __syncthreads();

    __shared__ float g[DEMB];
    __shared__ float h1[DH];
    __shared__ float h2[DH];
    if (t < DEMB) {
        float S = red2[0][0] + red2[1][0];
        g[t] = (red2[0][1 + t] + red2[1][1 + t]) / S;
    }
    __syncthreads();

    float s1 = b1[t];
#pragma unroll
    for (int i = 0; i < DEMB; i++) s1 = fmaf(g[i], W1[i * DH + t], s1);
    h1[t] = fmaxf(s1, 0.f);
    __syncthreads();

    float s2v = b2[t];
    for (int i = 0; i < DH; i++) s2v = fmaf(h1[i], W2[i * DH + t], s2v);
    h2[t] = fmaxf(s2v, 0.f);
    __syncthreads();

    if (t < 4) {
        float lg = bx[t];
        for (int i = 0; i < DH; i++) lg = fmaf(h2[i], Wx[i * 4 + t], lg);
        out[t] = lg / 10.0f;
    } else if (t == 4) {
        float v = by[0];
        for (int i = 0; i < DH; i++) v = fmaf(h2[i], Wy[i], v);
        out[4] = v;
    }
}

extern "C" void kernel_launch(void* const* d_in, const int* in_sizes, int n_in,
                              void* d_out, int out_size, void* d_ws, size_t ws_size,
                              hipStream_t stream) {
    const float* nodes   = (const float*)d_in[0];
    const int*   senders = (const int*)d_in[1];
    const int*   recvs   = (const int*)d_in[2];
    const float* W_enc   = (const float*)d_in[3];
    const float* b_enc   = (const float*)d_in[4];
    const float* W_inf   = (const float*)d_in[5];
    const float* b_inf   = (const float*)d_in[6];
    const float* W_emb   = (const float*)d_in[7];
    const float* b_emb   = (const float*)d_in[8];
    const float* W1      = (const float*)d_in[9];
    const float* b1      = (const float*)d_in[10];
    const float* W2      = (const float*)d_in[11];
    const float* b2      = (const float*)d_in[12];
    const float* Wy      = (const float*)d_in[13];
    const float* by      = (const float*)d_in[14];
    const float* Wx      = (const float*)d_in[15];
    const float* bx      = (const float*)d_in[16];
    float* out = (float*)d_out;

    const int n_nodes = in_sizes[0] / NF;   // 50000
    const int n_edges = in_sizes[1];        // 1600000
    const int nb64 = (n_nodes + 63) / 64;   // 782

    // workspace layout (floats):
    float* ws    = (float*)d_ws;
    float* p     = ws;                                    // [N]
    float* inflb = ws + n_nodes;                          // [N]
    float* embT  = ws + 2 * (size_t)n_nodes;              // [12][N]
    float* rep   = ws + 14 * (size_t)n_nodes;             // [128][N]
    float* psum  = ws + (14 + NSLICE) * (size_t)n_nodes;  // [nb64*14]

    hipLaunchKernelGGL(k1_node, dim3(nb64), dim3(256), 0, stream,
                       nodes, W_enc, b_enc, W_inf, b_inf, W_emb, b_emb,
                       p, inflb, embT, n_nodes);
    hipLaunchKernelGGL(k2_scatter, dim3(NSLICE * NRANGE), dim3(512), 0, stream,
                       senders, recvs, p, rep, n_nodes, n_edges);
    hipLaunchKernelGGL(k3_soft, dim3(nb64), dim3(256), 0, stream,
                       inflb, rep, embT, psum, n_nodes);
    hipLaunchKernelGGL(k4_head, dim3(1), dim3(128), 0, stream,
                       psum, W1, b1, W2, b2, Wy, by, Wx, bx, out, nb64);
}